// Round 9
// baseline (718.766 us; speedup 1.0000x reference)
//
#include <hip/hip_runtime.h>

typedef __attribute__((ext_vector_type(8))) short short8;
typedef __attribute__((ext_vector_type(4))) float f32x4;

#define T_TOK  131072
#define DMODEL 256
#define DHID   512
#define NEXP   8

// ---------------- ws layout (bytes) ----------------
// xb        : 0          size 67108864   (T*256 bf16)
// w1b       : 67108864   size 2097152
// w2b       : 69206016   size 2097152
// tok_list  : 71303168   size 4194304    (E*T int)
// wt_list   : 75497472   size 4194304    (E*T float)
// pack      : 79691776   size 524288     (T int)
// tkw       : 80216064   size 1048576    (T float2)
// part_cnt  : 81264640   size 65536      (2048*8 int)
// part_psum : 81526784   size 65536
// block_off : 81788928   size 65536
// cnt_total : 82051072   size 64         (int[16]: counts + bases)
// H         : 83886080   size 268566528  ((2T+128) x 512 bf16)

__device__ __forceinline__ unsigned short f2bf(float f) {
  unsigned int u = __float_as_uint(f);
  u = (u + 0x7FFFu + ((u >> 16) & 1u)) >> 16;
  return (unsigned short)u;
}

__device__ __forceinline__ void gload16(const void* g, void* l) {
  __builtin_amdgcn_global_load_lds(
      (const __attribute__((address_space(1))) void*)g,
      (__attribute__((address_space(3))) void*)l, 16, 0, 0);
}

// ---------------- weight fp32 -> bf16 ----------------
__global__ void k_wconv(const float* __restrict__ w1, const float* __restrict__ w2,
                        unsigned short* __restrict__ w1b, unsigned short* __restrict__ w2b) {
  int i = blockIdx.x * 256 + threadIdx.x;
  float4 a = ((const float4*)w1)[i];
  ushort4 ua; ua.x = f2bf(a.x); ua.y = f2bf(a.y); ua.z = f2bf(a.z); ua.w = f2bf(a.w);
  ((ushort4*)w1b)[i] = ua;
  float4 b = ((const float4*)w2)[i];
  ushort4 ub; ub.x = f2bf(b.x); ub.y = f2bf(b.y); ub.z = f2bf(b.z); ub.w = f2bf(b.w);
  ((ushort4*)w2b)[i] = ub;
}

// ---------------- router: fp64 logits (bit-identical math), 64 tok/block ----------------
__global__ __launch_bounds__(256) void k_router(
    const float* __restrict__ x, const float* __restrict__ gate,
    unsigned short* __restrict__ xb, int* __restrict__ pack, float2* __restrict__ tkw,
    int* __restrict__ part_cnt, float* __restrict__ part_psum) {
  __shared__ float g[NEXP][DMODEL];
  __shared__ int s_cnt[NEXP];
  __shared__ float s_ps[NEXP];
  int tid = threadIdx.x;
  for (int i = tid; i < NEXP * DMODEL; i += 256) g[i >> 8][i & 255] = gate[i];
  if (tid < NEXP) { s_cnt[tid] = 0; s_ps[tid] = 0.f; }
  __syncthreads();
  int lane = tid & 63, wv = tid >> 6;
  float psacc[NEXP] = {0.f,0.f,0.f,0.f,0.f,0.f,0.f,0.f};
  for (int k = 0; k < 16; ++k) {
    int t = (blockIdx.x << 6) + (wv << 4) + k;
    const float* xr = x + (size_t)t * DMODEL;
    float4 x4 = *(const float4*)(xr + 4 * lane);
    ushort4 u4;
    u4.x = f2bf(x4.x); u4.y = f2bf(x4.y); u4.z = f2bf(x4.z); u4.w = f2bf(x4.w);
    *(ushort4*)(xb + (size_t)t * DMODEL + 4 * lane) = u4;
    double l[NEXP];
#pragma unroll
    for (int e = 0; e < NEXP; ++e) {
      const float4 g4 = *(const float4*)&g[e][4 * lane];
      l[e] = (double)x4.x * (double)g4.x + (double)x4.y * (double)g4.y +
             (double)x4.z * (double)g4.z + (double)x4.w * (double)g4.w;
    }
#pragma unroll
    for (int e = 0; e < NEXP; ++e) {
#pragma unroll
      for (int d = 32; d; d >>= 1) l[e] += __shfl_xor(l[e], d);
    }
    int i1 = 0;
#pragma unroll
    for (int e = 1; e < NEXP; ++e) if (l[e] > l[i1]) i1 = e;
    int i2 = (i1 == 0) ? 1 : 0;
#pragma unroll
    for (int e = 0; e < NEXP; ++e) if (e != i1 && l[e] > l[i2]) i2 = e;
    double m = l[0];
#pragma unroll
    for (int e = 1; e < NEXP; ++e) m = (l[e] > m) ? l[e] : m;
    float pe[NEXP]; float s = 0.f;
#pragma unroll
    for (int e = 0; e < NEXP; ++e) { pe[e] = __expf((float)(l[e] - m)); s += pe[e]; }
    float inv = 1.f / s;
    float p1 = pe[i1] * inv, p2 = pe[i2] * inv;
    float wn = 1.f / (p1 + p2);
    if (lane == 0) {
      pack[t] = i1 | (i2 << 8);
      tkw[t] = make_float2(p1 * wn, p2 * wn);
      atomicAdd(&s_cnt[i1], 1); atomicAdd(&s_cnt[i2], 1);
#pragma unroll
      for (int e = 0; e < NEXP; ++e) psacc[e] += pe[e] * inv;
    }
  }
  if (lane == 0) {
#pragma unroll
    for (int e = 0; e < NEXP; ++e) atomicAdd(&s_ps[e], psacc[e]);
  }
  __syncthreads();
  if (tid < NEXP) {
    part_cnt[blockIdx.x * NEXP + tid] = s_cnt[tid];
    part_psum[blockIdx.x * NEXP + tid] = s_ps[tid];
  }
}

// ---------------- scan: offsets, totals, expert bases, aux loss ----------------
__global__ __launch_bounds__(512) void k_scan(
    const int* __restrict__ part_cnt, const float* __restrict__ part_psum,
    int* __restrict__ block_off, int* __restrict__ cnt_total, float* __restrict__ out) {
  __shared__ float s_ps[NEXP];
  __shared__ int s_ct[NEXP];
  int lane = threadIdx.x & 63, wv = threadIdx.x >> 6;
  int base = lane * 32;
  int lsum = 0; float ps = 0.f;
#pragma unroll 8
  for (int j = 0; j < 32; ++j) {
    lsum += part_cnt[(base + j) * NEXP + wv];
    ps += part_psum[(base + j) * NEXP + wv];
  }
  int incl = lsum;
#pragma unroll
  for (int d = 1; d < 64; d <<= 1) { int t = __shfl_up(incl, d); if (lane >= d) incl += t; }
  int run = incl - lsum;
#pragma unroll 8
  for (int j = 0; j < 32; ++j) {
    int v = part_cnt[(base + j) * NEXP + wv];
    block_off[(base + j) * NEXP + wv] = run;
    run += v;
  }
#pragma unroll
  for (int d = 32; d; d >>= 1) ps += __shfl_xor(ps, d);
  int total = __shfl(incl, 63);
  if (lane == 0) { cnt_total[wv] = total; s_ct[wv] = total; s_ps[wv] = ps; }
  __syncthreads();
  if (threadIdx.x == 0) {
    double aux = 0.0; int rb = 0;
    for (int e = 0; e < NEXP; ++e) {
      aux += ((double)s_ct[e] / 131072.0) * ((double)s_ps[e] / 131072.0);
      cnt_total[8 + e] = rb; rb += s_ct[e];
    }
    out[33554432] = (float)(8.0 * aux);
  }
}

// ---------------- scatter (matches router's 64-token blocking) ----------------
__global__ void k_scatter(const int* __restrict__ pack, const float2* __restrict__ tkw,
                          const int* __restrict__ block_off, int* __restrict__ tok_list,
                          float* __restrict__ wt_list) {
  __shared__ int s_loc[NEXP];
  int tid = threadIdx.x;
  if (tid < NEXP) s_loc[tid] = 0;
  __syncthreads();
  int t = (blockIdx.x << 6) + tid;
  int p = pack[t];
  float2 wv = tkw[t];
  int e1 = p & 255, e2 = (p >> 8) & 255;
  int o1 = block_off[blockIdx.x * NEXP + e1];
  int p1 = atomicAdd(&s_loc[e1], 1);
  tok_list[e1 * T_TOK + o1 + p1] = t;
  wt_list[e1 * T_TOK + o1 + p1] = wv.x;
  int o2 = block_off[blockIdx.x * NEXP + e2];
  int p2 = atomicAdd(&s_loc[e2], 1);
  tok_list[e2 * T_TOK + o2 + p2] = t;
  wt_list[e2 * T_TOK + o2 + p2] = wv.y;
}

// ---------------- grouped GEMM1 + silu: H = silu(X @ W1^T + b1) ----------------
// 256x256 tile (ni selects hid-half), K=DMODEL=256, BK=64 -> 4 K-steps
// (ROUND-8 BUG: this loop ran 8 steps, reading 2x past K; fixed to 4).
// 512 thr (2M x 4N waves, per-wave 128x64, acc[8][4]), 128KB dbuf LDS,
// 1 block/CU. 2-phase: issue stage(cc+1) -> compute cc -> vmcnt(0)+s_barrier.
// Chunk swizzle slot = r*8 + (chunk ^ (r&7)) on both sides.
__global__ __launch_bounds__(512, 2) void k_gemm1(
    const unsigned short* __restrict__ xb, const unsigned short* __restrict__ w1b,
    const float* __restrict__ b1, const int* __restrict__ tok_list,
    const int* __restrict__ cnt_total, unsigned short* __restrict__ H) {
  __shared__ __align__(16) unsigned short buf[65536];  // A: 2x16384 u16, B: 2x16384 u16
  __shared__ int s_tok[256];

  int bid = (blockIdx.x & 7) * 258 + (blockIdx.x >> 3);
  int e = -1, loc = 0, cum = 0, cnte = 0;
#pragma unroll
  for (int ee = 0; ee < NEXP; ++ee) {
    int ct = cnt_total[ee];
    int nb = ((ct + 255) >> 8) * 2;
    if (e < 0 && bid < cum + nb) { e = ee; loc = bid - cum; cnte = ct; }
    cum += nb;
  }
  if (e < 0) return;
  int mi = loc >> 1, ni = loc & 1;
  int nv = cnte - (mi << 8); if (nv > 256) nv = 256;

  int tid = threadIdx.x;
  int lane = tid & 63, w = tid >> 6, l15 = lane & 15, lg = lane >> 4;
  int wr = w >> 2, wc = w & 3;  // 2M x 4N wave grid; per-wave 128x64

  float b1v[4];
#pragma unroll
  for (int nt = 0; nt < 4; ++nt)
    b1v[nt] = b1[e * DHID + ni * 256 + wc * 64 + nt * 16 + l15];

  if (tid < 256) s_tok[tid] = tok_list[e * T_TOK + (mi << 8) + (tid < nv ? tid : nv - 1)];
  __syncthreads();

  // staging: slot s=i*512+tid -> row=i*64+(tid>>3), cslot=tid&7;
  // content chunk = cslot ^ (row&7)  (row&7 == (tid>>3)&7, i-independent)
  int srow = tid >> 3;
  int swz = (((tid & 7) ^ (srow & 7)) << 3);
  const unsigned short* w1e = w1b + ((size_t)e * DHID + ni * 256) * DMODEL;
  const unsigned short* pa[4];
  const unsigned short* pb[4];
#pragma unroll
  for (int i = 0; i < 4; ++i) {
    pa[i] = xb + (size_t)s_tok[i * 64 + srow] * DMODEL + swz;
    pb[i] = w1e + (size_t)(i * 64 + srow) * DMODEL + swz;
  }

  auto stage = [&](int cc) {
    int ab = (cc & 1) * 16384, bb = 32768 + (cc & 1) * 16384;
#pragma unroll
    for (int i = 0; i < 4; ++i)
      gload16(pa[i] + cc * 64, &buf[ab + (i * 512 + w * 64) * 8]);
#pragma unroll
    for (int i = 0; i < 4; ++i)
      gload16(pb[i] + cc * 64, &buf[bb + (i * 512 + w * 64) * 8]);
  };

  f32x4 acc[8][4];
#pragma unroll
  for (int mt = 0; mt < 8; ++mt)
#pragma unroll
    for (int nt = 0; nt < 4; ++nt) acc[mt][nt] = (f32x4){0.f, 0.f, 0.f, 0.f};

  stage(0);
  asm volatile("s_waitcnt vmcnt(0)" ::: "memory");
  __builtin_amdgcn_s_barrier();
  __builtin_amdgcn_sched_barrier(0);

  for (int cc = 0; cc < 4; ++cc) {          // K = 256, BK = 64 -> 4 steps
    if (cc < 3) stage(cc + 1);
    int ab = (cc & 1) * 16384, bb = 32768 + (cc & 1) * 16384;
#pragma unroll
    for (int ks = 0; ks < 2; ++ks) {
      short8 a[8], b[4];
#pragma unroll
      for (int mt = 0; mt < 8; ++mt) {
        int r = wr * 128 + mt * 16 + l15;
        a[mt] = *(const short8*)&buf[ab + (r * 8 + ((ks * 4 + lg) ^ (r & 7))) * 8];
      }
#pragma unroll
      for (int nt = 0; nt < 4; ++nt) {
        int r = wc * 64 + nt * 16 + l15;
        b[nt] = *(const short8*)&buf[bb + (r * 8 + ((ks * 4 + lg) ^ (r & 7))) * 8];
      }
#pragma unroll
      for (int mt = 0; mt < 8; ++mt)
#pragma unroll
        for (int nt = 0; nt < 4; ++nt)
          acc[mt][nt] = __builtin_amdgcn_mfma_f32_16x16x32_bf16(a[mt], b[nt], acc[mt][nt], 0, 0, 0);
    }
    asm volatile("s_waitcnt vmcnt(0)" ::: "memory");
    __builtin_amdgcn_s_barrier();
    __builtin_amdgcn_sched_barrier(0);
  }

  // epilogue: bias+silu -> LDS bounce (chunk ^ (row&7)) -> vectorized H store
#pragma unroll
  for (int mt = 0; mt < 8; ++mt)
#pragma unroll
    for (int nt = 0; nt < 4; ++nt)
#pragma unroll
      for (int rr = 0; rr < 4; ++rr) {
        int row = wr * 128 + mt * 16 + lg * 4 + rr;
        int col = wc * 64 + nt * 16 + l15;
        float z = acc[mt][nt][rr] + b1v[nt];
        float sv = z / (1.f + __expf(-z));
        buf[row * 256 + ((((col >> 3) ^ (row & 7))) << 3) + (col & 7)] = f2bf(sv);
      }
  __syncthreads();
  int hb = cnt_total[8 + e];
#pragma unroll
  for (int i = 0; i < 16; ++i) {
    int t = i * 512 + tid;
    int row = t >> 5, ch = t & 31;
    if (row < nv) {
      short8 v = *(const short8*)&buf[row * 256 + (((ch ^ (row & 7))) << 3)];
      *(short8*)&H[(size_t)(hb + (mi << 8) + row) * DHID + ni * 256 + (ch << 3)] = v;
    }
  }
}

// ---------------- grouped GEMM2 + scale + scatter: out += w*(H @ W2^T + b2) ----------------
// 256x256 tile (N = full DMODEL -> H staged ONCE), K=DHID=512, BK=64 -> 8 steps.
// A-row addresses clamped to nv-1 (no read past expert region at tails).
__global__ __launch_bounds__(512, 2) void k_gemm2(
    const unsigned short* __restrict__ H, const unsigned short* __restrict__ w2b,
    const float* __restrict__ b2, const int* __restrict__ tok_list,
    const float* __restrict__ wt_list, const int* __restrict__ cnt_total,
    float* __restrict__ out) {
  __shared__ __align__(16) unsigned short buf[65536];
  __shared__ int s_tok[256];
  __shared__ float s_wt[256];

  int bid = (blockIdx.x & 7) * 129 + (blockIdx.x >> 3);
  int e = -1, mi = 0, cum = 0, cnte = 0;
#pragma unroll
  for (int ee = 0; ee < NEXP; ++ee) {
    int ct = cnt_total[ee];
    int nb = (ct + 255) >> 8;
    if (e < 0 && bid < cum + nb) { e = ee; mi = bid - cum; cnte = ct; }
    cum += nb;
  }
  if (e < 0) return;
  int nv = cnte - (mi << 8); if (nv > 256) nv = 256;

  int tid = threadIdx.x;
  int lane = tid & 63, w = tid >> 6, l15 = lane & 15, lg = lane >> 4;
  int wr = w >> 2, wc = w & 3;

  float b2v[4];
#pragma unroll
  for (int nt = 0; nt < 4; ++nt)
    b2v[nt] = b2[e * DMODEL + wc * 64 + nt * 16 + l15];

  if (tid < 256) {
    int idx = e * T_TOK + (mi << 8) + (tid < nv ? tid : nv - 1);
    s_tok[tid] = tok_list[idx];
    s_wt[tid] = (tid < nv) ? wt_list[idx] : 0.f;
  }
  __syncthreads();

  int hb = cnt_total[8 + e];
  const unsigned short* hrows = H + (size_t)(hb + (mi << 8)) * DHID;
  const unsigned short* w2e = w2b + (size_t)e * DMODEL * DHID;

  int srow = tid >> 3;
  int swz = (((tid & 7) ^ (srow & 7)) << 3);
  const unsigned short* pa[4];
  const unsigned short* pb[4];
#pragma unroll
  for (int i = 0; i < 4; ++i) {
    int r = i * 64 + srow;
    int rc = (r < nv) ? r : (nv - 1);        // clamp: never read past expert's H rows
    pa[i] = hrows + (size_t)rc * DHID + swz;
    pb[i] = w2e + (size_t)(i * 64 + srow) * DHID + swz;
  }

  auto stage = [&](int cc) {
    int ab = (cc & 1) * 16384, bb = 32768 + (cc & 1) * 16384;
#pragma unroll
    for (int i = 0; i < 4; ++i)
      gload16(pa[i] + cc * 64, &buf[ab + (i * 512 + w * 64) * 8]);
#pragma unroll
    for (int i = 0; i < 4; ++i)
      gload16(pb[i] + cc * 64, &buf[bb + (i * 512 + w * 64) * 8]);
  };

  f32x4 acc[8][4];
#pragma unroll
  for (int mt = 0; mt < 8; ++mt)
#pragma unroll
    for (int nt = 0; nt < 4; ++nt) acc[mt][nt] = (f32x4){0.f, 0.f, 0.f, 0.f};

  stage(0);
  asm volatile("s_waitcnt vmcnt(0)" ::: "memory");
  __builtin_amdgcn_s_barrier();
  __builtin_amdgcn_sched_barrier(0);

  for (int cc = 0; cc < 8; ++cc) {          // K = 512, BK = 64 -> 8 steps
    if (cc < 7) stage(cc + 1);
    int ab = (cc & 1) * 16384, bb = 32768 + (cc & 1) * 16384;
#pragma unroll
    for (int ks = 0; ks < 2; ++ks) {
      short8 a[8], b[4];
#pragma unroll
      for (int mt = 0; mt < 8; ++mt) {
        int r = wr * 128 + mt * 16 + l15;
        a[mt] = *(const short8*)&buf[ab + (r * 8 + ((ks * 4 + lg) ^ (r & 7))) * 8];
      }
#pragma unroll
      for (int nt = 0; nt < 4; ++nt) {
        int r = wc * 64 + nt * 16 + l15;
        b[nt] = *(const short8*)&buf[bb + (r * 8 + ((ks * 4 + lg) ^ (r & 7))) * 8];
      }
#pragma unroll
      for (int mt = 0; mt < 8; ++mt)
#pragma unroll
        for (int nt = 0; nt < 4; ++nt)
          acc[mt][nt] = __builtin_amdgcn_mfma_f32_16x16x32_bf16(a[mt], b[nt], acc[mt][nt], 0, 0, 0);
    }
    asm volatile("s_waitcnt vmcnt(0)" ::: "memory");
    __builtin_amdgcn_s_barrier();
    __builtin_amdgcn_sched_barrier(0);
  }

  // epilogue: out[tok, col] += wt * (acc + b2[col])
#pragma unroll
  for (int mt = 0; mt < 8; ++mt)
#pragma unroll
    for (int rr = 0; rr < 4; ++rr) {
      int row = wr * 128 + mt * 16 + lg * 4 + rr;
      if (row < nv) {
        float wt = s_wt[row];
        float* orow = out + (size_t)s_tok[row] * DMODEL;
#pragma unroll
        for (int nt = 0; nt < 4; ++nt)
          atomicAdd(orow + wc * 64 + nt * 16 + l15, wt * (acc[mt][nt][rr] + b2v[nt]));
      }
    }
}

extern "C" void kernel_launch(void* const* d_in, const int* in_sizes, int n_in,
                              void* d_out, int out_size, void* d_ws, size_t ws_size,
                              hipStream_t stream) {
  const float* x    = (const float*)d_in[0];
  const float* gate = (const float*)d_in[1];
  const float* w1   = (const float*)d_in[2];
  const float* b1   = (const float*)d_in[3];
  const float* w2   = (const float*)d_in[4];
  const float* b2   = (const float*)d_in[5];
  float* out = (float*)d_out;
  char* ws = (char*)d_ws;

  unsigned short* xb  = (unsigned short*)(ws);
  unsigned short* w1b = (unsigned short*)(ws + 67108864);
  unsigned short* w2b = (unsigned short*)(ws + 69206016);
  int*    tok_list  = (int*)(ws + 71303168);
  float*  wt_list   = (float*)(ws + 75497472);
  int*    pack      = (int*)(ws + 79691776);
  float2* tkw       = (float2*)(ws + 80216064);
  int*    part_cnt  = (int*)(ws + 81264640);
  float*  part_psum = (float*)(ws + 81526784);
  int*    block_off = (int*)(ws + 81788928);
  int*    cnt_total = (int*)(ws + 82051072);
  unsigned short* H = (unsigned short*)(ws + 83886080);

  hipMemsetAsync(d_out, 0, (size_t)out_size * 4, stream);
  k_wconv<<<1024, 256, 0, stream>>>(w1, w2, w1b, w2b);
  k_router<<<2048, 256, 0, stream>>>(x, gate, xb, pack, tkw, part_cnt, part_psum);
  k_scan<<<1, 512, 0, stream>>>(part_cnt, part_psum, block_off, cnt_total, out);
  k_scatter<<<2048, 64, 0, stream>>>(pack, tkw, block_off, tok_list, wt_list);
  k_gemm1<<<2064, 512, 0, stream>>>(xb, w1b, b1, tok_list, cnt_total, H);
  k_gemm2<<<1032, 512, 0, stream>>>(H, w2b, b2, tok_list, wt_list, cnt_total, out);
}